// Round 7
// baseline (201.953 us; speedup 1.0000x reference)
//
#include <hip/hip_runtime.h>
#include <hip/hip_bf16.h>

#define B_  32
#define S_  1024
#define E_  768
#define HD_ 64
#define M_  (B_*S_)   // 32768 rows of x

typedef __attribute__((ext_vector_type(8))) short short8;   // 8 bf16 (4 VGPR)
typedef __attribute__((ext_vector_type(4))) float float4v;  // MFMA acc

// fp32 -> bf16 round-to-nearest-even
__device__ __forceinline__ unsigned short f2bf(float x) {
    union { float f; unsigned u; } c; c.f = x;
    unsigned r = (c.u + 0x7FFFu + ((c.u >> 16) & 1u)) >> 16;
    return (unsigned short)r;
}

// async global->LDS, 16B per lane; LDS dest = wave-uniform tile base.
__device__ __forceinline__ void gld_lds16(const void* g, void* l) {
    __builtin_amdgcn_global_load_lds(
        (const __attribute__((address_space(1))) unsigned int*)g,
        (__attribute__((address_space(3))) unsigned int*)l,
        16, 0, 0);
}

// ---------------------------------------------------------------------------
// Fused setup: RoPE tables (blocks 0..127), dtype sniffer -> flag (block 128),
// W pre-pack (blocks 129..200; inline per-block sniff avoids flag race).
// Wp[ct(12)][c(12)][ks(2)][lane(64)][8 bf16] fragment order (r3, verified).
// ---------------------------------------------------------------------------
__global__ __launch_bounds__(256) void setup_kernel(
    const unsigned int* __restrict__ xw,
    const void* __restrict__ Wq_, const void* __restrict__ Wk_,
    const void* __restrict__ Wv_,
    unsigned int* __restrict__ flag,
    float* __restrict__ cs_t, float* __restrict__ sn_t,
    unsigned short* __restrict__ wp)
{
    const int bx = blockIdx.x;
    if (bx < 128) {                     // RoPE tables
        int idx = bx * 256 + threadIdx.x;   // 0 .. 32767
        int pos = idx >> 5;
        int ii  = idx & 31;
        float theta = exp2f(-(float)ii * 0.8304820237218406f);  // log2(10000)/16
        float fr = (float)pos * theta;
        float sn, cs;
        sincosf(fr, &sn, &cs);
        cs_t[idx] = cs;
        sn_t[idx] = sn;
        return;
    }
    // blocks 128..200: sniff dtype (verified rounds 2-5 logic)
    __shared__ int cnt;
    if (threadIdx.x == 0) cnt = 0;
    __syncthreads();
    unsigned int w0 = xw[(size_t)threadIdx.x * 33331];
    unsigned int e0 = (w0 >> 8) & 0x7F;
    int hit = (e0 >= 0x3B && e0 <= 0x40) ? 1 : 0;
    atomicAdd(&cnt, hit);
    __syncthreads();
    const bool isb = (cnt > 128);
    if (bx == 128) {
        if (threadIdx.x == 0) *flag = isb ? 1u : 0u;
        return;
    }
    // wpack body (blocks 129..200 -> gid 0..18431)
    int gid  = (bx - 129) * 256 + threadIdx.x;
    int lane = gid & 63;
    int tIdx = gid >> 6;                          // 0..287
    int ct   = tIdx / 24;
    int rem  = tIdx - ct * 24;
    int c    = rem >> 1, ks = rem & 1;
    int quad = lane >> 4, l15 = lane & 15;
    const void* wsel = (ct < 4) ? Wq_ : (ct < 8 ? Wk_ : Wv_);
    int row = (ct & 3) * 16 + l15;
    int col = c * 64 + ks * 32 + quad * 8;
    uint4 w;
    if (isb) {
        w = *(const uint4*)((const unsigned short*)wsel + (size_t)row * E_ + col);
    } else {
        const float* f = (const float*)wsel + (size_t)row * E_ + col;
        float4 a = *(const float4*)f, bq = *(const float4*)(f + 4);
        w.x = f2bf(a.x)  | ((unsigned)f2bf(a.y)  << 16);
        w.y = f2bf(a.z)  | ((unsigned)f2bf(a.w)  << 16);
        w.z = f2bf(bq.x) | ((unsigned)f2bf(bq.y) << 16);
        w.w = f2bf(bq.z) | ((unsigned)f2bf(bq.w) << 16);
    }
    *(uint4*)(wp + (size_t)gid * 8) = w;
}

// ---------------------------------------------------------------------------
// QKV projection + RoPE, MFMA 16x16x32 bf16.
// ROUND-7 CHANGE: prefetch depth 1 -> 2 chunks (within the proven r5
// template). breg triple-buffered; A ring-3 unchanged (write (c+2)%3 vs
// read c%3 disjoint; WAR covered by the iter-c barrier as in r5).
// Steady state: 14 VMEM outstanding/wave; vmcnt(7) at top of iter c
// completes exactly B(c)x6 + A(c), leaving B(c+1)/A(c+1) in flight ->
// each load gets TWO compute phases + stall slack to cover L2/HBM latency.
// Uniform 7 VMEM issued per iter (clamped dummies into never-read slots).
// Block 512 thr (8 waves): wave h=w>>2 (2 mt), cw=w&3 (3 ct). Grid 512,
// 24 KB LDS, VGPR ~112 <= 128 -> 2 blocks/CU.
// ---------------------------------------------------------------------------
__global__ __launch_bounds__(512, 4) void qkv_mfma_kernel(
    const void* __restrict__ x_, const unsigned short* __restrict__ wp,
    const unsigned int* __restrict__ flag,
    const float* __restrict__ cs_t, const float* __restrict__ sn_t,
    unsigned short* __restrict__ rq_p, unsigned short* __restrict__ rk_p,
    unsigned short* __restrict__ vt_p)
{
    __shared__ __align__(16) char alds[3][8192];   // A ring

    const bool isb = (*flag != 0);
    const int t    = threadIdx.x;
    const int lane = t & 63;
    const int wave = t >> 6;        // 0..7
    const int quad = lane >> 4;
    const int l15  = lane & 15;
    const int row0 = blockIdx.x * 64;
    const int h    = wave >> 2;     // row half: mt tiles {h*2, h*2+1}
    const int cw   = wave & 3;      // col group: ct = cw*3 + nt

    // A stage descriptor: 1 instr/wave/chunk; wave covers rows wave*8..+7.
    const unsigned aRow = (unsigned)(wave * 8 + (lane >> 3));
    const unsigned eoA  = aRow * 768u + (unsigned)(((lane & 7) ^ (lane >> 3)) * 8);

    // A fragment read byte-addrs within a slot
    unsigned aA[2][2];
    #pragma unroll
    for (int mtl = 0; mtl < 2; ++mtl) {
        unsigned rl = (unsigned)((h * 2 + mtl) * 16 + l15);
        #pragma unroll
        for (int ks = 0; ks < 2; ++ks)
            aA[mtl][ks] = rl * 128u + ((((unsigned)ks << 2) | (unsigned)quad) ^ (rl & 7u)) * 16u;
    }

    // B fragment bases (chunk stride = 1024 elems)
    const unsigned short* wbase[3][2];
    #pragma unroll
    for (int nt = 0; nt < 3; ++nt) {
        int ct = cw * 3 + nt;
        #pragma unroll
        for (int ks = 0; ks < 2; ++ks)
            wbase[nt][ks] = wp + ((size_t)(ct * 24 + ks)) * 512 + lane * 8;
    }

    float4v acc[3][2];
    #pragma unroll
    for (int nt = 0; nt < 3; ++nt)
        #pragma unroll
        for (int mtl = 0; mtl < 2; ++mtl)
            #pragma unroll
            for (int r = 0; r < 4; ++r) acc[nt][mtl][r] = 0.f;

    short8 breg[3][3][2];   // TRIPLE-buffered B frags (static idx under unroll)

    const unsigned short* xb16 = (const unsigned short*)x_ + (size_t)row0 * E_;
    const float*          xb32 = (const float*)x_ + (size_t)row0 * E_;

    #define LOADB(cc, sel)                                                       \
        {   int tc_ = (cc) < 11 ? (cc) : 11;                                     \
            _Pragma("unroll")                                                    \
            for (int nt_ = 0; nt_ < 3; ++nt_)                                    \
                _Pragma("unroll")                                                \
                for (int ks_ = 0; ks_ < 2; ++ks_)                                \
                    breg[sel][nt_][ks_] =                                        \
                        *(const short8*)(wbase[nt_][ks_] + tc_ * 1024);          \
        }

    #define COMPUTE(cc, sel)                                                     \
        {   const char* sb_ = alds[(cc) % 3];                                    \
            _Pragma("unroll")                                                    \
            for (int ks_ = 0; ks_ < 2; ++ks_) {                                  \
                short8 af0 = *(const short8*)(sb_ + aA[0][ks_]);                 \
                short8 af1 = *(const short8*)(sb_ + aA[1][ks_]);                 \
                _Pragma("unroll")                                                \
                for (int nt_ = 0; nt_ < 3; ++nt_) {                              \
                    acc[nt_][0] = __builtin_amdgcn_mfma_f32_16x16x32_bf16(       \
                        af0, breg[sel][nt_][ks_], acc[nt_][0], 0, 0, 0);         \
                    acc[nt_][1] = __builtin_amdgcn_mfma_f32_16x16x32_bf16(       \
                        af1, breg[sel][nt_][ks_], acc[nt_][1], 0, 0, 0);         \
                }                                                                \
            }                                                                    \
        }

    if (isb) {
        // prologue depth-2: [B0 x6, A0, B1 x6, A1] = 14 outstanding VMEM
        LOADB(0, 0);
        __builtin_amdgcn_sched_barrier(0);
        gld_lds16(xb16 + eoA, alds[0] + wave * 1024);
        __builtin_amdgcn_sched_barrier(0);
        LOADB(1, 1);
        __builtin_amdgcn_sched_barrier(0);
        gld_lds16(xb16 + eoA + 64, alds[1] + wave * 1024);
        __builtin_amdgcn_sched_barrier(0);
        #pragma unroll
        for (int c = 0; c < 12; ++c) {
            // completes exactly B(c)x6 + A(c); leaves B(c+1)x6 + A(c+1) in flight
            asm volatile("s_waitcnt vmcnt(7)" ::: "memory");
            __builtin_amdgcn_s_barrier();
            // issue order pinned: B(c+2) x6 then A(c+2) x1 (uniform 7/iter)
            LOADB(c + 2, (c + 2) % 3);
            __builtin_amdgcn_sched_barrier(0);
            {
                int tc = (c + 2) < 11 ? (c + 2) : 11;
                gld_lds16(xb16 + eoA + tc * 64, alds[(c + 2) % 3] + wave * 1024);
            }
            __builtin_amdgcn_sched_barrier(0);
            COMPUTE(c, c % 3);
        }
    } else {
        // f32 correctness path: A via reg-convert ds_write, full syncs.
        auto stageA_f = [&](int c) {
            const float* f = xb32 + eoA + c * 64;
            float4 a = *(const float4*)f, bq = *(const float4*)(f + 4);
            uint4 w;
            w.x = f2bf(a.x)  | ((unsigned)f2bf(a.y)  << 16);
            w.y = f2bf(a.z)  | ((unsigned)f2bf(a.w)  << 16);
            w.z = f2bf(bq.x) | ((unsigned)f2bf(bq.y) << 16);
            w.w = f2bf(bq.z) | ((unsigned)f2bf(bq.w) << 16);
            *(uint4*)(alds[c % 3] + wave * 1024 + (size_t)lane * 16) = w;
        };
        stageA_f(0); stageA_f(1);
        LOADB(0, 0);
        LOADB(1, 1);
        __syncthreads();
        #pragma unroll
        for (int c = 0; c < 12; ++c) {
            if (c + 2 < 12) stageA_f(c + 2);
            LOADB(c + 2, (c + 2) % 3);
            COMPUTE(c, c % 3);
            __syncthreads();
        }
    }
    #undef LOADB
    #undef COMPUTE

    // ---- Epilogue (unchanged r3-r6, verified): C col=l15, row=quad*4+r.
    const int b      = row0 >> 10;
    const int s_in_b = row0 & (S_ - 1);
    #pragma unroll
    for (int nt = 0; nt < 3; ++nt) {
        int ct = cw * 3 + nt;
        int region = ct >> 2;          // 0=q, 1=k, 2=v (wave-uniform)
        int d = (ct & 3) * 16 + l15;
        if (region < 2) {
            unsigned short* dst = (region == 0) ? rq_p : rk_p;
            int ii = d >> 1;
            int ksq = d >> 5, quadq = (d >> 3) & 3, e = d & 7;
            #pragma unroll
            for (int mtl = 0; mtl < 2; ++mtl) {
                #pragma unroll
                for (int r = 0; r < 4; ++r) {
                    int row = row0 + (h * 2 + mtl) * 16 + quad * 4 + r;
                    int pos = row & (S_ - 1);
                    float cs = cs_t[pos * 32 + ii];
                    float sn = sn_t[pos * 32 + ii];
                    float val = acc[nt][mtl][r];
                    float partner = __shfl_xor(val, 1);   // pair col d^1 = lane^1
                    float res = (d & 1) ? fmaf(val, cs,  partner * sn)
                                        : fmaf(val, cs, -partner * sn);
                    int kt = pos >> 6, ntq = (pos >> 4) & 3, l15q = pos & 15;
                    size_t idx = ((((size_t)(b * 16 + kt) * 4 + ntq) * 2 + ksq) * 64
                                  + quadq * 16 + l15q) * 8 + e;
                    dst[idx] = f2bf(res);
                }
            }
        } else {
            int ntv = ct & 3;          // d = ntv*16 + l15
            #pragma unroll
            for (int mtl = 0; mtl < 2; ++mtl) {
                int sb2 = s_in_b + (h * 2 + mtl) * 16 + quad * 4;
                int kt = sb2 >> 6, ksv = (sb2 >> 5) & 1, quadv = (sb2 >> 3) & 3, e0 = sb2 & 7;
                ushort4 pk;
                pk.x = f2bf(acc[nt][mtl][0]);
                pk.y = f2bf(acc[nt][mtl][1]);
                pk.z = f2bf(acc[nt][mtl][2]);
                pk.w = f2bf(acc[nt][mtl][3]);
                size_t idx = ((((size_t)(b * 16 + kt) * 4 + ntv) * 2 + ksv) * 64
                              + quadv * 16 + l15) * 8 + e0;
                *(ushort4*)(vt_p + idx) = pk;
            }
        }
    }
}

// ---------------------------------------------------------------------------
// Flash attention — unchanged from round 6 (direct global->VGPR K/V from
// packed layouts; no barriers; ~19us, ~450 TF-equivalent).
// ---------------------------------------------------------------------------
__global__ __launch_bounds__(256, 2) void attn_mfma_kernel(
    const unsigned short* __restrict__ rq_p, const unsigned short* __restrict__ rk_p,
    const unsigned short* __restrict__ vt_p, const unsigned int* __restrict__ flag,
    void* __restrict__ out)
{
    __shared__ unsigned short plds[4][16][72];                 // per-wave P buffer

    const bool isb = (*flag != 0);
    const int t    = threadIdx.x;
    const int lane = t & 63;
    const int wave = t >> 6;
    const int quad = lane >> 4;
    const int l15  = lane & 15;
    const int qt   = blockIdx.x;
    const int b    = blockIdx.y;
    const int q0   = qt * 64 + wave * 16;
    const float scale = 0.03608439182435161f;   // 768^-0.5

    // Q A-frags from packed tile (b, kt=qt, nt=wave)
    const unsigned short* qb = rq_p + ((size_t)((b * 16 + qt) * 4 + wave) * 2) * 512;
    short8 qf0 = *(const short8*)(qb + lane * 8);
    short8 qf1 = *(const short8*)(qb + 512 + lane * 8);

    // packed tile base: tile (kt,nt,ks) at ((b*64 + kt*4 + nt)*2 + ks)*512 + lane*8
    const unsigned short* kb0 = rk_p + ((size_t)b * 128) * 512 + lane * 8;
    const unsigned short* vb0 = vt_p + ((size_t)b * 128) * 512 + lane * 8;

    float4v o[4];
    float m_[4], l_[4];
    #pragma unroll
    for (int nt = 0; nt < 4; ++nt)
        #pragma unroll
        for (int r = 0; r < 4; ++r) o[nt][r] = 0.f;
    #pragma unroll
    for (int r = 0; r < 4; ++r) { m_[r] = -1e30f; l_[r] = 0.f; }

    const int nIter = (qt + 2) >> 1;

    for (int i = 0; i < nIter; ++i) {
        const int ta = 2 * i;
        const int tb = min(ta + 1, qt);     // dup tail fully masked via logical kg
        const int ktv[2] = { ta, tb };

        // ---- K frags -> regs (coalesced 1KB/wave each) ----
        short8 kf[2][4][2];
        #pragma unroll
        for (int slot = 0; slot < 2; ++slot)
            #pragma unroll
            for (int nt = 0; nt < 4; ++nt)
                #pragma unroll
                for (int ks = 0; ks < 2; ++ks)
                    kf[slot][nt][ks] = *(const short8*)(
                        kb0 + (size_t)(ktv[slot] * 8 + nt * 2 + ks) * 512);

        // ---- S = Q K^T for both slots ----
        float sc[2][4][4];
        #pragma unroll
        for (int slot = 0; slot < 2; ++slot) {
            #pragma unroll
            for (int nt = 0; nt < 4; ++nt) {
                float4v s;
                #pragma unroll
                for (int r = 0; r < 4; ++r) s[r] = 0.f;
                s = __builtin_amdgcn_mfma_f32_16x16x32_bf16(qf0, kf[slot][nt][0], s, 0, 0, 0);
                s = __builtin_amdgcn_mfma_f32_16x16x32_bf16(qf1, kf[slot][nt][1], s, 0, 0, 0);
                #pragma unroll
                for (int r = 0; r < 4; ++r) sc[slot][nt][r] = s[r] * scale;
            }
        }

        // ---- V frags -> regs NOW (latency hides under softmax VALU) ----
        short8 vf[2][4][2];
        #pragma unroll
        for (int slot = 0; slot < 2; ++slot)
            #pragma unroll
            for (int nt = 0; nt < 4; ++nt)
                #pragma unroll
                for (int ks = 0; ks < 2; ++ks)
                    vf[slot][nt][ks] = *(const short8*)(
                        vb0 + (size_t)(ktv[slot] * 8 + nt * 2 + ks) * 512);

        // ---- causal mask (wave-uniform trigger near diagonal) ----
        if (2 * i + 1 >= qt) {
            #pragma unroll
            for (int slot = 0; slot < 2; ++slot) {
                int ktl = 2 * i + slot;     // LOGICAL tile (dup tail -> all masked)
                #pragma unroll
                for (int nt = 0; nt < 4; ++nt) {
                    int kg = ktl * 64 + nt * 16 + l15;
                    #pragma unroll
                    for (int r = 0; r < 4; ++r) {
                        int qg = q0 + quad * 4 + r;
                        if (kg > qg) sc[slot][nt][r] = -1e30f;
                    }
                }
            }
        }

        // ---- online softmax over 128 keys (16-lane reduce) ----
        float mx[4];
        #pragma unroll
        for (int r = 0; r < 4; ++r) {
            float a0 = fmaxf(fmaxf(sc[0][0][r], sc[0][1][r]), fmaxf(sc[0][2][r], sc[0][3][r]));
            float a1 = fmaxf(fmaxf(sc[1][0][r], sc[1][1][r]), fmaxf(sc[1][2][r], sc[1][3][r]));
            mx[r] = fmaxf(a0, a1);
        }
        #pragma unroll
        for (int st = 1; st < 16; st <<= 1)
            #pragma unroll
            for (int r = 0; r < 4; ++r)
                mx[r] = fmaxf(mx[r], __shfl_xor(mx[r], st));

        float al[4];
        #pragma unroll
        for (int r = 0; r < 4; ++r) {
            float mn = fmaxf(m_[r], mx[r]);
            al[r] = __expf(m_[r] - mn);
            m_[r] = mn;
        }

        float sm[4] = {0.f, 0.f, 0.f, 0.f};
        #pragma unroll
        for (int slot = 0; slot < 2; ++slot)
            #pragma unroll
            for (int nt = 0; nt < 4; ++nt)
                #pragma unroll
                for (int r = 0; r < 4; ++r) {
                    float p = __expf(sc[slot][nt][r] - m_[r]);
                    sc[slot][nt][r] = p;
                    sm[r] += p;
                }
        #pragma unroll
        for (int st = 1; st < 16; st <<= 1)
            #pragma unroll
            for (int r = 0; r < 4; ++r)
                sm[r] += __shfl_xor(sm[r], st);
        #pragma unroll
        for (int r = 0; r < 4; ++r) l_[r] = l_[r] * al[r] + sm[r];

        #pragma unroll
        for (int nt = 0; nt < 4; ++nt)
            #pragma unroll
            for (int r = 0; r < 4; ++r) o[nt][r] *= al[r];

        // ---- per slot: P -> plds (wave-local) -> A-frag; O += P V ----
        #pragma unroll
        for (int slot = 0; slot < 2; ++slot) {
            #pragma unroll
            for (int nt = 0; nt < 4; ++nt)
                #pragma unroll
                for (int r = 0; r < 4; ++r)
                    plds[wave][quad * 4 + r][nt * 16 + l15] = f2bf(sc[slot][nt][r]);
            short8 pf0 = *(const short8*)&plds[wave][l15][quad * 8];
            short8 pf1 = *(const short8*)&plds[wave][l15][32 + quad * 8];
            #pragma unroll
            for (int nt = 0; nt < 4; ++nt) {
                o[nt] = __builtin_amdgcn_mfma_f32_16x16x32_bf16(pf0, vf[slot][nt][0], o[nt], 0, 0, 0);
                o[nt] = __builtin_amdgcn_mfma_f32_16x16x32_bf16(pf1, vf[slot][nt][1], o[nt], 0, 0, 0);
            }
        }
    }

    // ---- epilogue: normalize, store per dtype ----
    float inv[4];
    #pragma unroll
    for (int r = 0; r < 4; ++r) inv[r] = 1.0f / l_[r];
    if (isb) {
        unsigned short* op = (unsigned short*)out;
        #pragma unroll
        for (int nt = 0; nt < 4; ++nt)
            #pragma unroll
            for (int r = 0; r < 4; ++r) {
                size_t row = (size_t)b * S_ + q0 + quad * 4 + r;
                op[row * HD_ + nt * 16 + l15] = f2bf(o[nt][r] * inv[r]);
            }
    } else {
        float* op = (float*)out;
        #pragma unroll
        for (int nt = 0; nt < 4; ++nt)
            #pragma unroll
            for (int r = 0; r < 4; ++r) {
                size_t row = (size_t)b * S_ + q0 + quad * 4 + r;
                op[row * HD_ + nt * 16 + l15] = o[nt][r] * inv[r];
            }
    }
}

// ---------------------------------------------------------------------------
extern "C" void kernel_launch(void* const* d_in, const int* in_sizes, int n_in,
                              void* d_out, int out_size, void* d_ws, size_t ws_size,
                              hipStream_t stream) {
    const void* x  = d_in[0];
    const void* Wq = d_in[1];
    const void* Wk = d_in[2];
    const void* Wv = d_in[3];

    // ws layout (~12.9 MB)
    unsigned int* flag = (unsigned int*)d_ws;
    float* cs_t = (float*)d_ws + 64;
    float* sn_t = cs_t + (size_t)S_ * 32;
    unsigned short* wp   = (unsigned short*)(sn_t + (size_t)S_ * 32);  // 288 tiles
    unsigned short* rq_p = wp + (size_t)288 * 512;
    unsigned short* rk_p = rq_p + (size_t)M_ * HD_;
    unsigned short* vt_p = rk_p + (size_t)M_ * HD_;

    hipLaunchKernelGGL(setup_kernel, dim3(201), dim3(256), 0, stream,
                       (const unsigned int*)x, Wq, Wk, Wv, flag, cs_t, sn_t, wp);
    hipLaunchKernelGGL(qkv_mfma_kernel, dim3(M_ / 64), dim3(512), 0, stream,
                       x, wp, flag, cs_t, sn_t, rq_p, rk_p, vt_p);
    hipLaunchKernelGGL(attn_mfma_kernel, dim3(S_ / 64, B_), dim3(256), 0, stream,
                       rq_p, rk_p, vt_p, flag, d_out);
}

// Round 8
// 191.053 us; speedup vs baseline: 1.0570x; 1.0570x over previous
//
#include <hip/hip_runtime.h>
#include <hip/hip_bf16.h>

#define B_  32
#define S_  1024
#define E_  768
#define HD_ 64
#define M_  (B_*S_)   // 32768 rows of x
#define WREP 8               // wp replicas (L2 hotspot spread)
#define WPSZ 147456          // elems per wp replica (288 tiles x 512)

typedef __attribute__((ext_vector_type(8))) short short8;   // 8 bf16 (4 VGPR)
typedef __attribute__((ext_vector_type(4))) float float4v;  // MFMA acc

// fp32 -> bf16 round-to-nearest-even
__device__ __forceinline__ unsigned short f2bf(float x) {
    union { float f; unsigned u; } c; c.f = x;
    unsigned r = (c.u + 0x7FFFu + ((c.u >> 16) & 1u)) >> 16;
    return (unsigned short)r;
}

// async global->LDS, 16B per lane; LDS dest = wave-uniform tile base.
__device__ __forceinline__ void gld_lds16(const void* g, void* l) {
    __builtin_amdgcn_global_load_lds(
        (const __attribute__((address_space(1))) unsigned int*)g,
        (__attribute__((address_space(3))) unsigned int*)l,
        16, 0, 0);
}

// ---------------------------------------------------------------------------
// Fused setup: RoPE tables (blocks 0..127), dtype sniffer -> flag (block 128),
// W pre-pack x8 REPLICAS (blocks 129..704; inline per-block sniff).
// Wp[rep][ct(12)][c(12)][ks(2)][lane(64)][8 bf16]; replicas bit-identical.
// ---------------------------------------------------------------------------
__global__ __launch_bounds__(256) void setup_kernel(
    const unsigned int* __restrict__ xw,
    const void* __restrict__ Wq_, const void* __restrict__ Wk_,
    const void* __restrict__ Wv_,
    unsigned int* __restrict__ flag,
    float* __restrict__ cs_t, float* __restrict__ sn_t,
    unsigned short* __restrict__ wp)
{
    const int bx = blockIdx.x;
    if (bx < 128) {                     // RoPE tables
        int idx = bx * 256 + threadIdx.x;   // 0 .. 32767
        int pos = idx >> 5;
        int ii  = idx & 31;
        float theta = exp2f(-(float)ii * 0.8304820237218406f);  // log2(10000)/16
        float fr = (float)pos * theta;
        float sn, cs;
        sincosf(fr, &sn, &cs);
        cs_t[idx] = cs;
        sn_t[idx] = sn;
        return;
    }
    // blocks 128..704: sniff dtype (verified logic)
    __shared__ int cnt;
    if (threadIdx.x == 0) cnt = 0;
    __syncthreads();
    unsigned int w0 = xw[(size_t)threadIdx.x * 33331];
    unsigned int e0 = (w0 >> 8) & 0x7F;
    int hit = (e0 >= 0x3B && e0 <= 0x40) ? 1 : 0;
    atomicAdd(&cnt, hit);
    __syncthreads();
    const bool isb = (cnt > 128);
    if (bx == 128) {
        if (threadIdx.x == 0) *flag = isb ? 1u : 0u;
        return;
    }
    // wpack body: blocks 129..704 -> rep = (bx-129)/72, inner block (bx-129)%72
    int rep  = (bx - 129) / 72;
    int bxin = (bx - 129) - rep * 72;
    int gid  = bxin * 256 + threadIdx.x;          // 0..18431
    int lane = gid & 63;
    int tIdx = gid >> 6;                          // 0..287
    int ct   = tIdx / 24;
    int rem  = tIdx - ct * 24;
    int c    = rem >> 1, ks = rem & 1;
    int quad = lane >> 4, l15 = lane & 15;
    const void* wsel = (ct < 4) ? Wq_ : (ct < 8 ? Wk_ : Wv_);
    int row = (ct & 3) * 16 + l15;
    int col = c * 64 + ks * 32 + quad * 8;
    uint4 w;
    if (isb) {
        w = *(const uint4*)((const unsigned short*)wsel + (size_t)row * E_ + col);
    } else {
        const float* f = (const float*)wsel + (size_t)row * E_ + col;
        float4 a = *(const float4*)f, bq = *(const float4*)(f + 4);
        w.x = f2bf(a.x)  | ((unsigned)f2bf(a.y)  << 16);
        w.y = f2bf(a.z)  | ((unsigned)f2bf(a.w)  << 16);
        w.z = f2bf(bq.x) | ((unsigned)f2bf(bq.y) << 16);
        w.w = f2bf(bq.z) | ((unsigned)f2bf(bq.w) << 16);
    }
    *(uint4*)(wp + (size_t)rep * WPSZ + (size_t)gid * 8) = w;
}

// ---------------------------------------------------------------------------
// QKV projection + RoPE, MFMA 16x16x32 bf16.
// ROUND-8 CHANGES (r7's depth-2 retried spill-free + L2 de-hotspot):
// 1. LATE-ISSUE depth-2: breg stays DOUBLE-buffered (48 VGPR, r5-proven);
//    B(c+2) issued AFTER COMPUTE(c) into the just-consumed buffer (values
//    dead -> regalloc reuses the same VGPRs; sched_barrier pins lifetimes).
//    Steady state 14 VMEM outstanding; vmcnt(7) at top completes exactly
//    B(c)x6+A(c) -> every load gets ~2 compute phases of slack.
// 2. wp replica (blockIdx.x & 7): 512 blocks no longer hammer the same
//    288KB of L2 lines in lockstep (suspected L2-slice serialization).
// FIFO: prologue [B0x6, A0, B1x6, A1]; iter c: vmcnt(7) -> barrier ->
// gldA(c+2) -> COMPUTE(c) -> LOADB(c+2 into c&1). Dummies clamped past end.
// Block 512 thr (8 waves): wave h=w>>2 (2 mt), cw=w&3 (3 ct). Grid 512,
// 24 KB LDS, breg[2] -> ~95 VGPR, 2 blocks/CU.
// ---------------------------------------------------------------------------
__global__ __launch_bounds__(512, 4) void qkv_mfma_kernel(
    const void* __restrict__ x_, const unsigned short* __restrict__ wp,
    const unsigned int* __restrict__ flag,
    const float* __restrict__ cs_t, const float* __restrict__ sn_t,
    unsigned short* __restrict__ rq_p, unsigned short* __restrict__ rk_p,
    unsigned short* __restrict__ vt_p)
{
    __shared__ __align__(16) char alds[3][8192];   // A ring

    const bool isb = (*flag != 0);
    const int t    = threadIdx.x;
    const int lane = t & 63;
    const int wave = t >> 6;        // 0..7
    const int quad = lane >> 4;
    const int l15  = lane & 15;
    const int row0 = blockIdx.x * 64;
    const int h    = wave >> 2;     // row half: mt tiles {h*2, h*2+1}
    const int cw   = wave & 3;      // col group: ct = cw*3 + nt

    // this block's wp replica
    const unsigned short* wpr = wp + (size_t)(blockIdx.x & (WREP - 1)) * WPSZ;

    // A stage descriptor: 1 instr/wave/chunk; wave covers rows wave*8..+7.
    const unsigned aRow = (unsigned)(wave * 8 + (lane >> 3));
    const unsigned eoA  = aRow * 768u + (unsigned)(((lane & 7) ^ (lane >> 3)) * 8);

    // A fragment read byte-addrs within a slot
    unsigned aA[2][2];
    #pragma unroll
    for (int mtl = 0; mtl < 2; ++mtl) {
        unsigned rl = (unsigned)((h * 2 + mtl) * 16 + l15);
        #pragma unroll
        for (int ks = 0; ks < 2; ++ks)
            aA[mtl][ks] = rl * 128u + ((((unsigned)ks << 2) | (unsigned)quad) ^ (rl & 7u)) * 16u;
    }

    // B fragment bases (chunk stride = 1024 elems)
    const unsigned short* wbase[3][2];
    #pragma unroll
    for (int nt = 0; nt < 3; ++nt) {
        int ct = cw * 3 + nt;
        #pragma unroll
        for (int ks = 0; ks < 2; ++ks)
            wbase[nt][ks] = wpr + ((size_t)(ct * 24 + ks)) * 512 + lane * 8;
    }

    float4v acc[3][2];
    #pragma unroll
    for (int nt = 0; nt < 3; ++nt)
        #pragma unroll
        for (int mtl = 0; mtl < 2; ++mtl)
            #pragma unroll
            for (int r = 0; r < 4; ++r) acc[nt][mtl][r] = 0.f;

    short8 breg[2][3][2];   // DOUBLE-buffered B frags (r5-proven allocation)

    const unsigned short* xb16 = (const unsigned short*)x_ + (size_t)row0 * E_;
    const float*          xb32 = (const float*)x_ + (size_t)row0 * E_;

    #define LOADB(cc, sel)                                                       \
        {   int tc_ = (cc) < 11 ? (cc) : 11;                                     \
            _Pragma("unroll")                                                    \
            for (int nt_ = 0; nt_ < 3; ++nt_)                                    \
                _Pragma("unroll")                                                \
                for (int ks_ = 0; ks_ < 2; ++ks_)                                \
                    breg[sel][nt_][ks_] =                                        \
                        *(const short8*)(wbase[nt_][ks_] + tc_ * 1024);          \
        }

    #define COMPUTE(cc, sel)                                                     \
        {   const char* sb_ = alds[(cc) % 3];                                    \
            _Pragma("unroll")                                                    \
            for (int ks_ = 0; ks_ < 2; ++ks_) {                                  \
                short8 af0 = *(const short8*)(sb_ + aA[0][ks_]);                 \
                short8 af1 = *(const short8*)(sb_ + aA[1][ks_]);                 \
                _Pragma("unroll")                                                \
                for (int nt_ = 0; nt_ < 3; ++nt_) {                              \
                    acc[nt_][0] = __builtin_amdgcn_mfma_f32_16x16x32_bf16(       \
                        af0, breg[sel][nt_][ks_], acc[nt_][0], 0, 0, 0);         \
                    acc[nt_][1] = __builtin_amdgcn_mfma_f32_16x16x32_bf16(       \
                        af1, breg[sel][nt_][ks_], acc[nt_][1], 0, 0, 0);         \
                }                                                                \
            }                                                                    \
        }

    if (isb) {
        // prologue FIFO: [B0 x6, A0, B1 x6, A1] = 14 outstanding
        LOADB(0, 0);
        __builtin_amdgcn_sched_barrier(0);
        gld_lds16(xb16 + eoA, alds[0] + wave * 1024);
        __builtin_amdgcn_sched_barrier(0);
        LOADB(1, 1);
        __builtin_amdgcn_sched_barrier(0);
        gld_lds16(xb16 + eoA + 64, alds[1] + wave * 1024);
        __builtin_amdgcn_sched_barrier(0);
        #pragma unroll
        for (int c = 0; c < 12; ++c) {
            // completes exactly B(c)x6 + A(c); leaves B(c+1)x6 + A(c+1)
            asm volatile("s_waitcnt vmcnt(7)" ::: "memory");
            __builtin_amdgcn_s_barrier();
            {   // A(c+2) -> ring slot (disjoint from read slot c%3)
                int tc = (c + 2) < 11 ? (c + 2) : 11;
                gld_lds16(xb16 + eoA + tc * 64, alds[(c + 2) % 3] + wave * 1024);
            }
            __builtin_amdgcn_sched_barrier(0);
            COMPUTE(c, c & 1);
            __builtin_amdgcn_sched_barrier(0);
            // late-issue B(c+2) into the buffer COMPUTE(c) just consumed
            LOADB(c + 2, c & 1);
            __builtin_amdgcn_sched_barrier(0);
        }
    } else {
        // f32 correctness path: A via reg-convert ds_write, full syncs (r5).
        auto stageA_f = [&](int c) {
            const float* f = xb32 + eoA + c * 64;
            float4 a = *(const float4*)f, bq = *(const float4*)(f + 4);
            uint4 w;
            w.x = f2bf(a.x)  | ((unsigned)f2bf(a.y)  << 16);
            w.y = f2bf(a.z)  | ((unsigned)f2bf(a.w)  << 16);
            w.z = f2bf(bq.x) | ((unsigned)f2bf(bq.y) << 16);
            w.w = f2bf(bq.z) | ((unsigned)f2bf(bq.w) << 16);
            *(uint4*)(alds[c % 3] + wave * 1024 + (size_t)lane * 16) = w;
        };
        stageA_f(0); stageA_f(1);
        LOADB(0, 0);
        __syncthreads();
        #pragma unroll
        for (int c = 0; c < 12; ++c) {
            if (c + 2 < 12) stageA_f(c + 2);
            LOADB(c + 1, (c + 1) & 1);
            COMPUTE(c, c & 1);
            __syncthreads();
        }
    }
    #undef LOADB
    #undef COMPUTE

    // ---- Epilogue (unchanged r3-r7, verified): C col=l15, row=quad*4+r.
    const int b      = row0 >> 10;
    const int s_in_b = row0 & (S_ - 1);
    #pragma unroll
    for (int nt = 0; nt < 3; ++nt) {
        int ct = cw * 3 + nt;
        int region = ct >> 2;          // 0=q, 1=k, 2=v (wave-uniform)
        int d = (ct & 3) * 16 + l15;
        if (region < 2) {
            unsigned short* dst = (region == 0) ? rq_p : rk_p;
            int ii = d >> 1;
            int ksq = d >> 5, quadq = (d >> 3) & 3, e = d & 7;
            #pragma unroll
            for (int mtl = 0; mtl < 2; ++mtl) {
                #pragma unroll
                for (int r = 0; r < 4; ++r) {
                    int row = row0 + (h * 2 + mtl) * 16 + quad * 4 + r;
                    int pos = row & (S_ - 1);
                    float cs = cs_t[pos * 32 + ii];
                    float sn = sn_t[pos * 32 + ii];
                    float val = acc[nt][mtl][r];
                    float partner = __shfl_xor(val, 1);   // pair col d^1 = lane^1
                    float res = (d & 1) ? fmaf(val, cs,  partner * sn)
                                        : fmaf(val, cs, -partner * sn);
                    int kt = pos >> 6, ntq = (pos >> 4) & 3, l15q = pos & 15;
                    size_t idx = ((((size_t)(b * 16 + kt) * 4 + ntq) * 2 + ksq) * 64
                                  + quadq * 16 + l15q) * 8 + e;
                    dst[idx] = f2bf(res);
                }
            }
        } else {
            int ntv = ct & 3;          // d = ntv*16 + l15
            #pragma unroll
            for (int mtl = 0; mtl < 2; ++mtl) {
                int sb2 = s_in_b + (h * 2 + mtl) * 16 + quad * 4;
                int kt = sb2 >> 6, ksv = (sb2 >> 5) & 1, quadv = (sb2 >> 3) & 3, e0 = sb2 & 7;
                ushort4 pk;
                pk.x = f2bf(acc[nt][mtl][0]);
                pk.y = f2bf(acc[nt][mtl][1]);
                pk.z = f2bf(acc[nt][mtl][2]);
                pk.w = f2bf(acc[nt][mtl][3]);
                size_t idx = ((((size_t)(b * 16 + kt) * 4 + ntv) * 2 + ksv) * 64
                              + quadv * 16 + l15) * 8 + e0;
                *(ushort4*)(vt_p + idx) = pk;
            }
        }
    }
}

// ---------------------------------------------------------------------------
// Flash attention — unchanged from round 6 (direct global->VGPR K/V from
// packed layouts; no barriers; ~19us).
// ---------------------------------------------------------------------------
__global__ __launch_bounds__(256, 2) void attn_mfma_kernel(
    const unsigned short* __restrict__ rq_p, const unsigned short* __restrict__ rk_p,
    const unsigned short* __restrict__ vt_p, const unsigned int* __restrict__ flag,
    void* __restrict__ out)
{
    __shared__ unsigned short plds[4][16][72];                 // per-wave P buffer

    const bool isb = (*flag != 0);
    const int t    = threadIdx.x;
    const int lane = t & 63;
    const int wave = t >> 6;
    const int quad = lane >> 4;
    const int l15  = lane & 15;
    const int qt   = blockIdx.x;
    const int b    = blockIdx.y;
    const int q0   = qt * 64 + wave * 16;
    const float scale = 0.03608439182435161f;   // 768^-0.5

    // Q A-frags from packed tile (b, kt=qt, nt=wave)
    const unsigned short* qb = rq_p + ((size_t)((b * 16 + qt) * 4 + wave) * 2) * 512;
    short8 qf0 = *(const short8*)(qb + lane * 8);
    short8 qf1 = *(const short8*)(qb + 512 + lane * 8);

    // packed tile base: tile (kt,nt,ks) at ((b*64 + kt*4 + nt)*2 + ks)*512 + lane*8
    const unsigned short* kb0 = rk_p + ((size_t)b * 128) * 512 + lane * 8;
    const unsigned short* vb0 = vt_p + ((size_t)b * 128) * 512 + lane * 8;

    float4v o[4];
    float m_[4], l_[4];
    #pragma unroll
    for (int nt = 0; nt < 4; ++nt)
        #pragma unroll
        for (int r = 0; r < 4; ++r) o[nt][r] = 0.f;
    #pragma unroll
    for (int r = 0; r < 4; ++r) { m_[r] = -1e30f; l_[r] = 0.f; }

    const int nIter = (qt + 2) >> 1;

    for (int i = 0; i < nIter; ++i) {
        const int ta = 2 * i;
        const int tb = min(ta + 1, qt);     // dup tail fully masked via logical kg
        const int ktv[2] = { ta, tb };

        // ---- K frags -> regs (coalesced 1KB/wave each) ----
        short8 kf[2][4][2];
        #pragma unroll
        for (int slot = 0; slot < 2; ++slot)
            #pragma unroll
            for (int nt = 0; nt < 4; ++nt)
                #pragma unroll
                for (int ks = 0; ks < 2; ++ks)
                    kf[slot][nt][ks] = *(const short8*)(
                        kb0 + (size_t)(ktv[slot] * 8 + nt * 2 + ks) * 512);

        // ---- S = Q K^T for both slots ----
        float sc[2][4][4];
        #pragma unroll
        for (int slot = 0; slot < 2; ++slot) {
            #pragma unroll
            for (int nt = 0; nt < 4; ++nt) {
                float4v s;
                #pragma unroll
                for (int r = 0; r < 4; ++r) s[r] = 0.f;
                s = __builtin_amdgcn_mfma_f32_16x16x32_bf16(qf0, kf[slot][nt][0], s, 0, 0, 0);
                s = __builtin_amdgcn_mfma_f32_16x16x32_bf16(qf1, kf[slot][nt][1], s, 0, 0, 0);
                #pragma unroll
                for (int r = 0; r < 4; ++r) sc[slot][nt][r] = s[r] * scale;
            }
        }

        // ---- V frags -> regs NOW (latency hides under softmax VALU) ----
        short8 vf[2][4][2];
        #pragma unroll
        for (int slot = 0; slot < 2; ++slot)
            #pragma unroll
            for (int nt = 0; nt < 4; ++nt)
                #pragma unroll
                for (int ks = 0; ks < 2; ++ks)
                    vf[slot][nt][ks] = *(const short8*)(
                        vb0 + (size_t)(ktv[slot] * 8 + nt * 2 + ks) * 512);

        // ---- causal mask (wave-uniform trigger near diagonal) ----
        if (2 * i + 1 >= qt) {
            #pragma unroll
            for (int slot = 0; slot < 2; ++slot) {
                int ktl = 2 * i + slot;     // LOGICAL tile (dup tail -> all masked)
                #pragma unroll
                for (int nt = 0; nt < 4; ++nt) {
                    int kg = ktl * 64 + nt * 16 + l15;
                    #pragma unroll
                    for (int r = 0; r < 4; ++r) {
                        int qg = q0 + quad * 4 + r;
                        if (kg > qg) sc[slot][nt][r] = -1e30f;
                    }
                }
            }
        }

        // ---- online softmax over 128 keys (16-lane reduce) ----
        float mx[4];
        #pragma unroll
        for (int r = 0; r < 4; ++r) {
            float a0 = fmaxf(fmaxf(sc[0][0][r], sc[0][1][r]), fmaxf(sc[0][2][r], sc[0][3][r]));
            float a1 = fmaxf(fmaxf(sc[1][0][r], sc[1][1][r]), fmaxf(sc[1][2][r], sc[1][3][r]));
            mx[r] = fmaxf(a0, a1);
        }
        #pragma unroll
        for (int st = 1; st < 16; st <<= 1)
            #pragma unroll
            for (int r = 0; r < 4; ++r)
                mx[r] = fmaxf(mx[r], __shfl_xor(mx[r], st));

        float al[4];
        #pragma unroll
        for (int r = 0; r < 4; ++r) {
            float mn = fmaxf(m_[r], mx[r]);
            al[r] = __expf(m_[r] - mn);
            m_[r] = mn;
        }

        float sm[4] = {0.f, 0.f, 0.f, 0.f};
        #pragma unroll
        for (int slot = 0; slot < 2; ++slot)
            #pragma unroll
            for (int nt = 0; nt < 4; ++nt)
                #pragma unroll
                for (int r = 0; r < 4; ++r) {
                    float p = __expf(sc[slot][nt][r] - m_[r]);
                    sc[slot][nt][r] = p;
                    sm[r] += p;
                }
        #pragma unroll
        for (int st = 1; st < 16; st <<= 1)
            #pragma unroll
            for (int r = 0; r < 4; ++r)
                sm[r] += __shfl_xor(sm[r], st);
        #pragma unroll
        for (int r = 0; r < 4; ++r) l_[r] = l_[r] * al[r] + sm[r];

        #pragma unroll
        for (int nt = 0; nt < 4; ++nt)
            #pragma unroll
            for (int r = 0; r < 4; ++r) o[nt][r] *= al[r];

        // ---- per slot: P -> plds (wave-local) -> A-frag; O += P V ----
        #pragma unroll
        for (int slot = 0; slot < 2; ++slot) {
            #pragma unroll
            for (int nt = 0; nt < 4; ++nt)
                #pragma unroll
                for (int r = 0; r < 4; ++r)
                    plds[wave][quad * 4 + r][nt * 16 + l15] = f2bf(sc[slot][nt][r]);
            short8 pf0 = *(const short8*)&plds[wave][l15][quad * 8];
            short8 pf1 = *(const short8*)&plds[wave][l15][32 + quad * 8];
            #pragma unroll
            for (int nt = 0; nt < 4; ++nt) {
                o[nt] = __builtin_amdgcn_mfma_f32_16x16x32_bf16(pf0, vf[slot][nt][0], o[nt], 0, 0, 0);
                o[nt] = __builtin_amdgcn_mfma_f32_16x16x32_bf16(pf1, vf[slot][nt][1], o[nt], 0, 0, 0);
            }
        }
    }

    // ---- epilogue: normalize, store per dtype ----
    float inv[4];
    #pragma unroll
    for (int r = 0; r < 4; ++r) inv[r] = 1.0f / l_[r];
    if (isb) {
        unsigned short* op = (unsigned short*)out;
        #pragma unroll
        for (int nt = 0; nt < 4; ++nt)
            #pragma unroll
            for (int r = 0; r < 4; ++r) {
                size_t row = (size_t)b * S_ + q0 + quad * 4 + r;
                op[row * HD_ + nt * 16 + l15] = f2bf(o[nt][r] * inv[r]);
            }
    } else {
        float* op = (float*)out;
        #pragma unroll
        for (int nt = 0; nt < 4; ++nt)
            #pragma unroll
            for (int r = 0; r < 4; ++r) {
                size_t row = (size_t)b * S_ + q0 + quad * 4 + r;
                op[row * HD_ + nt * 16 + l15] = o[nt][r] * inv[r];
            }
    }
}

// ---------------------------------------------------------------------------
extern "C" void kernel_launch(void* const* d_in, const int* in_sizes, int n_in,
                              void* d_out, int out_size, void* d_ws, size_t ws_size,
                              hipStream_t stream) {
    const void* x  = d_in[0];
    const void* Wq = d_in[1];
    const void* Wk = d_in[2];
    const void* Wv = d_in[3];

    // ws layout (~15 MB)
    unsigned int* flag = (unsigned int*)d_ws;
    float* cs_t = (float*)d_ws + 64;
    float* sn_t = cs_t + (size_t)S_ * 32;
    unsigned short* wp   = (unsigned short*)(sn_t + (size_t)S_ * 32);  // 8 replicas
    unsigned short* rq_p = wp + (size_t)WREP * WPSZ;
    unsigned short* rk_p = rq_p + (size_t)M_ * HD_;
    unsigned short* vt_p = rk_p + (size_t)M_ * HD_;

    hipLaunchKernelGGL(setup_kernel, dim3(129 + 72 * WREP), dim3(256), 0, stream,
                       (const unsigned int*)x, Wq, Wk, Wv, flag, cs_t, sn_t, wp);
    hipLaunchKernelGGL(qkv_mfma_kernel, dim3(M_ / 64), dim3(512), 0, stream,
                       x, wp, flag, cs_t, sn_t, rq_p, rk_p, vt_p);
    hipLaunchKernelGGL(attn_mfma_kernel, dim3(S_ / 64, B_), dim3(256), 0, stream,
                       rq_p, rk_p, vt_p, flag, d_out);
}

// Round 9
// 188.029 us; speedup vs baseline: 1.0741x; 1.0161x over previous
//
#include <hip/hip_runtime.h>
#include <hip/hip_bf16.h>

#define B_  32
#define S_  1024
#define E_  768
#define HD_ 64
#define M_  (B_*S_)   // 32768 rows of x
#define WREP 8               // wp replicas (L2 hotspot spread)
#define WPSZ 147456          // elems per wp replica (288 tiles x 512)

typedef __attribute__((ext_vector_type(8))) short short8;   // 8 bf16 (4 VGPR)
typedef __attribute__((ext_vector_type(4))) float float4v;  // MFMA acc

// fp32 -> bf16 round-to-nearest-even
__device__ __forceinline__ unsigned short f2bf(float x) {
    union { float f; unsigned u; } c; c.f = x;
    unsigned r = (c.u + 0x7FFFu + ((c.u >> 16) & 1u)) >> 16;
    return (unsigned short)r;
}

// async global->LDS, 16B per lane; LDS dest = wave-uniform tile base.
__device__ __forceinline__ void gld_lds16(const void* g, void* l) {
    __builtin_amdgcn_global_load_lds(
        (const __attribute__((address_space(1))) unsigned int*)g,
        (__attribute__((address_space(3))) unsigned int*)l,
        16, 0, 0);
}

// ---------------------------------------------------------------------------
// Fused setup: RoPE tables (blocks 0..127), dtype sniffer -> flag (block 128),
// W pre-pack x8 REPLICAS (blocks 129..704; inline per-block sniff).
// Wp[rep][ct(12)][c(12)][ks(2)][lane(64)][8 bf16]; replicas bit-identical.
// ---------------------------------------------------------------------------
__global__ __launch_bounds__(256) void setup_kernel(
    const unsigned int* __restrict__ xw,
    const void* __restrict__ Wq_, const void* __restrict__ Wk_,
    const void* __restrict__ Wv_,
    unsigned int* __restrict__ flag,
    float* __restrict__ cs_t, float* __restrict__ sn_t,
    unsigned short* __restrict__ wp)
{
    const int bx = blockIdx.x;
    if (bx < 128) {                     // RoPE tables
        int idx = bx * 256 + threadIdx.x;   // 0 .. 32767
        int pos = idx >> 5;
        int ii  = idx & 31;
        float theta = exp2f(-(float)ii * 0.8304820237218406f);  // log2(10000)/16
        float fr = (float)pos * theta;
        float sn, cs;
        sincosf(fr, &sn, &cs);
        cs_t[idx] = cs;
        sn_t[idx] = sn;
        return;
    }
    // blocks 128..704: sniff dtype (verified logic)
    __shared__ int cnt;
    if (threadIdx.x == 0) cnt = 0;
    __syncthreads();
    unsigned int w0 = xw[(size_t)threadIdx.x * 33331];
    unsigned int e0 = (w0 >> 8) & 0x7F;
    int hit = (e0 >= 0x3B && e0 <= 0x40) ? 1 : 0;
    atomicAdd(&cnt, hit);
    __syncthreads();
    const bool isb = (cnt > 128);
    if (bx == 128) {
        if (threadIdx.x == 0) *flag = isb ? 1u : 0u;
        return;
    }
    // wpack body: blocks 129..704 -> rep = (bx-129)/72, inner block (bx-129)%72
    int rep  = (bx - 129) / 72;
    int bxin = (bx - 129) - rep * 72;
    int gid  = bxin * 256 + threadIdx.x;          // 0..18431
    int lane = gid & 63;
    int tIdx = gid >> 6;                          // 0..287
    int ct   = tIdx / 24;
    int rem  = tIdx - ct * 24;
    int c    = rem >> 1, ks = rem & 1;
    int quad = lane >> 4, l15 = lane & 15;
    const void* wsel = (ct < 4) ? Wq_ : (ct < 8 ? Wk_ : Wv_);
    int row = (ct & 3) * 16 + l15;
    int col = c * 64 + ks * 32 + quad * 8;
    uint4 w;
    if (isb) {
        w = *(const uint4*)((const unsigned short*)wsel + (size_t)row * E_ + col);
    } else {
        const float* f = (const float*)wsel + (size_t)row * E_ + col;
        float4 a = *(const float4*)f, bq = *(const float4*)(f + 4);
        w.x = f2bf(a.x)  | ((unsigned)f2bf(a.y)  << 16);
        w.y = f2bf(a.z)  | ((unsigned)f2bf(a.w)  << 16);
        w.z = f2bf(bq.x) | ((unsigned)f2bf(bq.y) << 16);
        w.w = f2bf(bq.z) | ((unsigned)f2bf(bq.w) << 16);
    }
    *(uint4*)(wp + (size_t)rep * WPSZ + (size_t)gid * 8) = w;
}

// ---------------------------------------------------------------------------
// QKV projection + RoPE — UNCHANGED from round 8 (r5-proven template +
// late-issue depth-2 + wp replica; measured ≈47us, plateau at ~205 TF eff).
// ---------------------------------------------------------------------------
__global__ __launch_bounds__(512, 4) void qkv_mfma_kernel(
    const void* __restrict__ x_, const unsigned short* __restrict__ wp,
    const unsigned int* __restrict__ flag,
    const float* __restrict__ cs_t, const float* __restrict__ sn_t,
    unsigned short* __restrict__ rq_p, unsigned short* __restrict__ rk_p,
    unsigned short* __restrict__ vt_p)
{
    __shared__ __align__(16) char alds[3][8192];   // A ring

    const bool isb = (*flag != 0);
    const int t    = threadIdx.x;
    const int lane = t & 63;
    const int wave = t >> 6;        // 0..7
    const int quad = lane >> 4;
    const int l15  = lane & 15;
    const int row0 = blockIdx.x * 64;
    const int h    = wave >> 2;     // row half: mt tiles {h*2, h*2+1}
    const int cw   = wave & 3;      // col group: ct = cw*3 + nt

    // this block's wp replica
    const unsigned short* wpr = wp + (size_t)(blockIdx.x & (WREP - 1)) * WPSZ;

    // A stage descriptor: 1 instr/wave/chunk; wave covers rows wave*8..+7.
    const unsigned aRow = (unsigned)(wave * 8 + (lane >> 3));
    const unsigned eoA  = aRow * 768u + (unsigned)(((lane & 7) ^ (lane >> 3)) * 8);

    // A fragment read byte-addrs within a slot
    unsigned aA[2][2];
    #pragma unroll
    for (int mtl = 0; mtl < 2; ++mtl) {
        unsigned rl = (unsigned)((h * 2 + mtl) * 16 + l15);
        #pragma unroll
        for (int ks = 0; ks < 2; ++ks)
            aA[mtl][ks] = rl * 128u + ((((unsigned)ks << 2) | (unsigned)quad) ^ (rl & 7u)) * 16u;
    }

    // B fragment bases (chunk stride = 1024 elems)
    const unsigned short* wbase[3][2];
    #pragma unroll
    for (int nt = 0; nt < 3; ++nt) {
        int ct = cw * 3 + nt;
        #pragma unroll
        for (int ks = 0; ks < 2; ++ks)
            wbase[nt][ks] = wpr + ((size_t)(ct * 24 + ks)) * 512 + lane * 8;
    }

    float4v acc[3][2];
    #pragma unroll
    for (int nt = 0; nt < 3; ++nt)
        #pragma unroll
        for (int mtl = 0; mtl < 2; ++mtl)
            #pragma unroll
            for (int r = 0; r < 4; ++r) acc[nt][mtl][r] = 0.f;

    short8 breg[2][3][2];   // DOUBLE-buffered B frags (r5-proven allocation)

    const unsigned short* xb16 = (const unsigned short*)x_ + (size_t)row0 * E_;
    const float*          xb32 = (const float*)x_ + (size_t)row0 * E_;

    #define LOADB(cc, sel)                                                       \
        {   int tc_ = (cc) < 11 ? (cc) : 11;                                     \
            _Pragma("unroll")                                                    \
            for (int nt_ = 0; nt_ < 3; ++nt_)                                    \
                _Pragma("unroll")                                                \
                for (int ks_ = 0; ks_ < 2; ++ks_)                                \
                    breg[sel][nt_][ks_] =                                        \
                        *(const short8*)(wbase[nt_][ks_] + tc_ * 1024);          \
        }

    #define COMPUTE(cc, sel)                                                     \
        {   const char* sb_ = alds[(cc) % 3];                                    \
            _Pragma("unroll")                                                    \
            for (int ks_ = 0; ks_ < 2; ++ks_) {                                  \
                short8 af0 = *(const short8*)(sb_ + aA[0][ks_]);                 \
                short8 af1 = *(const short8*)(sb_ + aA[1][ks_]);                 \
                _Pragma("unroll")                                                \
                for (int nt_ = 0; nt_ < 3; ++nt_) {                              \
                    acc[nt_][0] = __builtin_amdgcn_mfma_f32_16x16x32_bf16(       \
                        af0, breg[sel][nt_][ks_], acc[nt_][0], 0, 0, 0);         \
                    acc[nt_][1] = __builtin_amdgcn_mfma_f32_16x16x32_bf16(       \
                        af1, breg[sel][nt_][ks_], acc[nt_][1], 0, 0, 0);         \
                }                                                                \
            }                                                                    \
        }

    if (isb) {
        // prologue FIFO: [B0 x6, A0, B1 x6, A1] = 14 outstanding
        LOADB(0, 0);
        __builtin_amdgcn_sched_barrier(0);
        gld_lds16(xb16 + eoA, alds[0] + wave * 1024);
        __builtin_amdgcn_sched_barrier(0);
        LOADB(1, 1);
        __builtin_amdgcn_sched_barrier(0);
        gld_lds16(xb16 + eoA + 64, alds[1] + wave * 1024);
        __builtin_amdgcn_sched_barrier(0);
        #pragma unroll
        for (int c = 0; c < 12; ++c) {
            // completes exactly B(c)x6 + A(c); leaves B(c+1)x6 + A(c+1)
            asm volatile("s_waitcnt vmcnt(7)" ::: "memory");
            __builtin_amdgcn_s_barrier();
            {   // A(c+2) -> ring slot (disjoint from read slot c%3)
                int tc = (c + 2) < 11 ? (c + 2) : 11;
                gld_lds16(xb16 + eoA + tc * 64, alds[(c + 2) % 3] + wave * 1024);
            }
            __builtin_amdgcn_sched_barrier(0);
            COMPUTE(c, c & 1);
            __builtin_amdgcn_sched_barrier(0);
            // late-issue B(c+2) into the buffer COMPUTE(c) just consumed
            LOADB(c + 2, c & 1);
            __builtin_amdgcn_sched_barrier(0);
        }
    } else {
        // f32 correctness path: A via reg-convert ds_write, full syncs (r5).
        auto stageA_f = [&](int c) {
            const float* f = xb32 + eoA + c * 64;
            float4 a = *(const float4*)f, bq = *(const float4*)(f + 4);
            uint4 w;
            w.x = f2bf(a.x)  | ((unsigned)f2bf(a.y)  << 16);
            w.y = f2bf(a.z)  | ((unsigned)f2bf(a.w)  << 16);
            w.z = f2bf(bq.x) | ((unsigned)f2bf(bq.y) << 16);
            w.w = f2bf(bq.z) | ((unsigned)f2bf(bq.w) << 16);
            *(uint4*)(alds[c % 3] + wave * 1024 + (size_t)lane * 16) = w;
        };
        stageA_f(0); stageA_f(1);
        LOADB(0, 0);
        __syncthreads();
        #pragma unroll
        for (int c = 0; c < 12; ++c) {
            if (c + 2 < 12) stageA_f(c + 2);
            LOADB(c + 1, (c + 1) & 1);
            COMPUTE(c, c & 1);
            __syncthreads();
        }
    }
    #undef LOADB
    #undef COMPUTE

    // ---- Epilogue (unchanged r3-r8, verified): C col=l15, row=quad*4+r.
    const int b      = row0 >> 10;
    const int s_in_b = row0 & (S_ - 1);
    #pragma unroll
    for (int nt = 0; nt < 3; ++nt) {
        int ct = cw * 3 + nt;
        int region = ct >> 2;          // 0=q, 1=k, 2=v (wave-uniform)
        int d = (ct & 3) * 16 + l15;
        if (region < 2) {
            unsigned short* dst = (region == 0) ? rq_p : rk_p;
            int ii = d >> 1;
            int ksq = d >> 5, quadq = (d >> 3) & 3, e = d & 7;
            #pragma unroll
            for (int mtl = 0; mtl < 2; ++mtl) {
                #pragma unroll
                for (int r = 0; r < 4; ++r) {
                    int row = row0 + (h * 2 + mtl) * 16 + quad * 4 + r;
                    int pos = row & (S_ - 1);
                    float cs = cs_t[pos * 32 + ii];
                    float sn = sn_t[pos * 32 + ii];
                    float val = acc[nt][mtl][r];
                    float partner = __shfl_xor(val, 1);   // pair col d^1 = lane^1
                    float res = (d & 1) ? fmaf(val, cs,  partner * sn)
                                        : fmaf(val, cs, -partner * sn);
                    int kt = pos >> 6, ntq = (pos >> 4) & 3, l15q = pos & 15;
                    size_t idx = ((((size_t)(b * 16 + kt) * 4 + ntq) * 2 + ksq) * 64
                                  + quadq * 16 + l15q) * 8 + e;
                    dst[idx] = f2bf(res);
                }
            }
        } else {
            int ntv = ct & 3;          // d = ntv*16 + l15
            #pragma unroll
            for (int mtl = 0; mtl < 2; ++mtl) {
                int sb2 = s_in_b + (h * 2 + mtl) * 16 + quad * 4;
                int kt = sb2 >> 6, ksv = (sb2 >> 5) & 1, quadv = (sb2 >> 3) & 3, e0 = sb2 & 7;
                ushort4 pk;
                pk.x = f2bf(acc[nt][mtl][0]);
                pk.y = f2bf(acc[nt][mtl][1]);
                pk.z = f2bf(acc[nt][mtl][2]);
                pk.w = f2bf(acc[nt][mtl][3]);
                size_t idx = ((((size_t)(b * 16 + kt) * 4 + ntv) * 2 + ksv) * 64
                              + quadv * 16 + l15) * 8 + e0;
                *(ushort4*)(vt_p + idx) = pk;
            }
        }
    }
}

// ---------------------------------------------------------------------------
// Flash attention — ROUND-9 CHANGE: causal LOAD-BALANCE remap. Work per
// block ∝ (qt+2)/2 (1..8 iters). Blocks dispatch round-robin over 8 XCDs,
// so co-resident CU pairs are linear ids (g, g+256); with qt fast-varying a
// CU could host two qt=15 blocks (16 iters vs mean 9.5). Remap so pairs get
// complementary qt (sum of iters = 9.5, constant):
//   g < 256:  qt = g & 15,        b = g >> 4
//   g >= 256: qt = 15 - (j & 15), b = 16 + (j >> 4),  j = g - 256
// Bijective over (qt,b). Compute/mask/epilogue byte-identical to r6/r8.
// Grid 512 (flattened), block 256 (4 independent waves).
// ---------------------------------------------------------------------------
__global__ __launch_bounds__(256, 2) void attn_mfma_kernel(
    const unsigned short* __restrict__ rq_p, const unsigned short* __restrict__ rk_p,
    const unsigned short* __restrict__ vt_p, const unsigned int* __restrict__ flag,
    void* __restrict__ out)
{
    __shared__ unsigned short plds[4][16][72];                 // per-wave P buffer

    const bool isb = (*flag != 0);
    const int t    = threadIdx.x;
    const int lane = t & 63;
    const int wave = t >> 6;
    const int quad = lane >> 4;
    const int l15  = lane & 15;

    // balance remap: co-resident pair (g, g+256) -> complementary qt
    const int g  = blockIdx.x;
    const int j  = g & 255;
    const int qt = (g < 256) ? (j & 15) : (15 - (j & 15));
    const int b  = (g < 256) ? (j >> 4) : (16 + (j >> 4));

    const int q0   = qt * 64 + wave * 16;
    const float scale = 0.03608439182435161f;   // 768^-0.5

    // Q A-frags from packed tile (b, kt=qt, nt=wave)
    const unsigned short* qb = rq_p + ((size_t)((b * 16 + qt) * 4 + wave) * 2) * 512;
    short8 qf0 = *(const short8*)(qb + lane * 8);
    short8 qf1 = *(const short8*)(qb + 512 + lane * 8);

    // packed tile base: tile (kt,nt,ks) at ((b*64 + kt*4 + nt)*2 + ks)*512 + lane*8
    const unsigned short* kb0 = rk_p + ((size_t)b * 128) * 512 + lane * 8;
    const unsigned short* vb0 = vt_p + ((size_t)b * 128) * 512 + lane * 8;

    float4v o[4];
    float m_[4], l_[4];
    #pragma unroll
    for (int nt = 0; nt < 4; ++nt)
        #pragma unroll
        for (int r = 0; r < 4; ++r) o[nt][r] = 0.f;
    #pragma unroll
    for (int r = 0; r < 4; ++r) { m_[r] = -1e30f; l_[r] = 0.f; }

    const int nIter = (qt + 2) >> 1;

    for (int i = 0; i < nIter; ++i) {
        const int ta = 2 * i;
        const int tb = min(ta + 1, qt);     // dup tail fully masked via logical kg
        const int ktv[2] = { ta, tb };

        // ---- K frags -> regs (coalesced 1KB/wave each) ----
        short8 kf[2][4][2];
        #pragma unroll
        for (int slot = 0; slot < 2; ++slot)
            #pragma unroll
            for (int nt = 0; nt < 4; ++nt)
                #pragma unroll
                for (int ks = 0; ks < 2; ++ks)
                    kf[slot][nt][ks] = *(const short8*)(
                        kb0 + (size_t)(ktv[slot] * 8 + nt * 2 + ks) * 512);

        // ---- S = Q K^T for both slots ----
        float sc[2][4][4];
        #pragma unroll
        for (int slot = 0; slot < 2; ++slot) {
            #pragma unroll
            for (int nt = 0; nt < 4; ++nt) {
                float4v s;
                #pragma unroll
                for (int r = 0; r < 4; ++r) s[r] = 0.f;
                s = __builtin_amdgcn_mfma_f32_16x16x32_bf16(qf0, kf[slot][nt][0], s, 0, 0, 0);
                s = __builtin_amdgcn_mfma_f32_16x16x32_bf16(qf1, kf[slot][nt][1], s, 0, 0, 0);
                #pragma unroll
                for (int r = 0; r < 4; ++r) sc[slot][nt][r] = s[r] * scale;
            }
        }

        // ---- V frags -> regs NOW (latency hides under softmax VALU) ----
        short8 vf[2][4][2];
        #pragma unroll
        for (int slot = 0; slot < 2; ++slot)
            #pragma unroll
            for (int nt = 0; nt < 4; ++nt)
                #pragma unroll
                for (int ks = 0; ks < 2; ++ks)
                    vf[slot][nt][ks] = *(const short8*)(
                        vb0 + (size_t)(ktv[slot] * 8 + nt * 2 + ks) * 512);

        // ---- causal mask (wave-uniform trigger near diagonal) ----
        if (2 * i + 1 >= qt) {
            #pragma unroll
            for (int slot = 0; slot < 2; ++slot) {
                int ktl = 2 * i + slot;     // LOGICAL tile (dup tail -> all masked)
                #pragma unroll
                for (int nt = 0; nt < 4; ++nt) {
                    int kg = ktl * 64 + nt * 16 + l15;
                    #pragma unroll
                    for (int r = 0; r < 4; ++r) {
                        int qg = q0 + quad * 4 + r;
                        if (kg > qg) sc[slot][nt][r] = -1e30f;
                    }
                }
            }
        }

        // ---- online softmax over 128 keys (16-lane reduce) ----
        float mx[4];
        #pragma unroll
        for (int r = 0; r < 4; ++r) {
            float a0 = fmaxf(fmaxf(sc[0][0][r], sc[0][1][r]), fmaxf(sc[0][2][r], sc[0][3][r]));
            float a1 = fmaxf(fmaxf(sc[1][0][r], sc[1][1][r]), fmaxf(sc[1][2][r], sc[1][3][r]));
            mx[r] = fmaxf(a0, a1);
        }
        #pragma unroll
        for (int st = 1; st < 16; st <<= 1)
            #pragma unroll
            for (int r = 0; r < 4; ++r)
                mx[r] = fmaxf(mx[r], __shfl_xor(mx[r], st));

        float al[4];
        #pragma unroll
        for (int r = 0; r < 4; ++r) {
            float mn = fmaxf(m_[r], mx[r]);
            al[r] = __expf(m_[r] - mn);
            m_[r] = mn;
        }

        float sm[4] = {0.f, 0.f, 0.f, 0.f};
        #pragma unroll
        for (int slot = 0; slot < 2; ++slot)
            #pragma unroll
            for (int nt = 0; nt < 4; ++nt)
                #pragma unroll
                for (int r = 0; r < 4; ++r) {
                    float p = __expf(sc[slot][nt][r] - m_[r]);
                    sc[slot][nt][r] = p;
                    sm[r] += p;
                }
        #pragma unroll
        for (int st = 1; st < 16; st <<= 1)
            #pragma unroll
            for (int r = 0; r < 4; ++r)
                sm[r] += __shfl_xor(sm[r], st);
        #pragma unroll
        for (int r = 0; r < 4; ++r) l_[r] = l_[r] * al[r] + sm[r];

        #pragma unroll
        for (int nt = 0; nt < 4; ++nt)
            #pragma unroll
            for (int r = 0; r < 4; ++r) o[nt][r] *= al[r];

        // ---- per slot: P -> plds (wave-local) -> A-frag; O += P V ----
        #pragma unroll
        for (int slot = 0; slot < 2; ++slot) {
            #pragma unroll
            for (int nt = 0; nt < 4; ++nt)
                #pragma unroll
                for (int r = 0; r < 4; ++r)
                    plds[wave][quad * 4 + r][nt * 16 + l15] = f2bf(sc[slot][nt][r]);
            short8 pf0 = *(const short8*)&plds[wave][l15][quad * 8];
            short8 pf1 = *(const short8*)&plds[wave][l15][32 + quad * 8];
            #pragma unroll
            for (int nt = 0; nt < 4; ++nt) {
                o[nt] = __builtin_amdgcn_mfma_f32_16x16x32_bf16(pf0, vf[slot][nt][0], o[nt], 0, 0, 0);
                o[nt] = __builtin_amdgcn_mfma_f32_16x16x32_bf16(pf1, vf[slot][nt][1], o[nt], 0, 0, 0);
            }
        }
    }

    // ---- epilogue: normalize, store per dtype ----
    float inv[4];
    #pragma unroll
    for (int r = 0; r < 4; ++r) inv[r] = 1.0f / l_[r];
    if (isb) {
        unsigned short* op = (unsigned short*)out;
        #pragma unroll
        for (int nt = 0; nt < 4; ++nt)
            #pragma unroll
            for (int r = 0; r < 4; ++r) {
                size_t row = (size_t)b * S_ + q0 + quad * 4 + r;
                op[row * HD_ + nt * 16 + l15] = f2bf(o[nt][r] * inv[r]);
            }
    } else {
        float* op = (float*)out;
        #pragma unroll
        for (int nt = 0; nt < 4; ++nt)
            #pragma unroll
            for (int r = 0; r < 4; ++r) {
                size_t row = (size_t)b * S_ + q0 + quad * 4 + r;
                op[row * HD_ + nt * 16 + l15] = o[nt][r] * inv[r];
            }
    }
}

// ---------------------------------------------------------------------------
extern "C" void kernel_launch(void* const* d_in, const int* in_sizes, int n_in,
                              void* d_out, int out_size, void* d_ws, size_t ws_size,
                              hipStream_t stream) {
    const void* x  = d_in[0];
    const void* Wq = d_in[1];
    const void* Wk = d_in[2];
    const void* Wv = d_in[3];

    // ws layout (~15 MB)
    unsigned int* flag = (unsigned int*)d_ws;
    float* cs_t = (float*)d_ws + 64;
    float* sn_t = cs_t + (size_t)S_ * 32;
    unsigned short* wp   = (unsigned short*)(sn_t + (size_t)S_ * 32);  // 8 replicas
    unsigned short* rq_p = wp + (size_t)WREP * WPSZ;
    unsigned short* rk_p = rq_p + (size_t)M_ * HD_;
    unsigned short* vt_p = rk_p + (size_t)M_ * HD_;

    hipLaunchKernelGGL(setup_kernel, dim3(129 + 72 * WREP), dim3(256), 0, stream,
                       (const unsigned int*)x, Wq, Wk, Wv, flag, cs_t, sn_t, wp);
    hipLaunchKernelGGL(qkv_mfma_kernel, dim3(M_ / 64), dim3(512), 0, stream,
                       x, wp, flag, cs_t, sn_t, rq_p, rk_p, vt_p);
    hipLaunchKernelGGL(attn_mfma_kernel, dim3(512), dim3(256), 0, stream,
                       rq_p, rk_p, vt_p, flag, d_out);
}

// Round 10
// 187.585 us; speedup vs baseline: 1.0766x; 1.0024x over previous
//
#include <hip/hip_runtime.h>
#include <hip/hip_bf16.h>

#define B_  32
#define S_  1024
#define E_  768
#define HD_ 64
#define M_  (B_*S_)   // 32768 rows of x
#define WREP 8               // wp replicas (XCD-aligned: block g -> XCD g%8)
#define WPSZ 147456          // elems per wp replica (288 tiles x 512)

typedef __attribute__((ext_vector_type(8))) short short8;   // 8 bf16 (4 VGPR)
typedef __attribute__((ext_vector_type(4))) float float4v;  // MFMA acc

// fp32 -> bf16 round-to-nearest-even
__device__ __forceinline__ unsigned short f2bf(float x) {
    union { float f; unsigned u; } c; c.f = x;
    unsigned r = (c.u + 0x7FFFu + ((c.u >> 16) & 1u)) >> 16;
    return (unsigned short)r;
}

// async global->LDS, 16B per lane; LDS dest = wave-uniform tile base.
__device__ __forceinline__ void gld_lds16(const void* g, void* l) {
    __builtin_amdgcn_global_load_lds(
        (const __attribute__((address_space(1))) unsigned int*)g,
        (__attribute__((address_space(3))) unsigned int*)l,
        16, 0, 0);
}

// ---------------------------------------------------------------------------
// Fused setup: RoPE tables (blocks 0..127), dtype sniffer -> flag (block 128),
// W pre-pack x8 REPLICAS (blocks 129..704; inline per-block sniff).
// Wp[rep][ct(12)][c(12)][ks(2)][lane(64)][8 bf16]; replicas bit-identical.
// ---------------------------------------------------------------------------
__global__ __launch_bounds__(256) void setup_kernel(
    const unsigned int* __restrict__ xw,
    const void* __restrict__ Wq_, const void* __restrict__ Wk_,
    const void* __restrict__ Wv_,
    unsigned int* __restrict__ flag,
    float* __restrict__ cs_t, float* __restrict__ sn_t,
    unsigned short* __restrict__ wp)
{
    const int bx = blockIdx.x;
    if (bx < 128) {                     // RoPE tables
        int idx = bx * 256 + threadIdx.x;   // 0 .. 32767
        int pos = idx >> 5;
        int ii  = idx & 31;
        float theta = exp2f(-(float)ii * 0.8304820237218406f);  // log2(10000)/16
        float fr = (float)pos * theta;
        float sn, cs;
        sincosf(fr, &sn, &cs);
        cs_t[idx] = cs;
        sn_t[idx] = sn;
        return;
    }
    // blocks 128..704: sniff dtype (verified logic)
    __shared__ int cnt;
    if (threadIdx.x == 0) cnt = 0;
    __syncthreads();
    unsigned int w0 = xw[(size_t)threadIdx.x * 33331];
    unsigned int e0 = (w0 >> 8) & 0x7F;
    int hit = (e0 >= 0x3B && e0 <= 0x40) ? 1 : 0;
    atomicAdd(&cnt, hit);
    __syncthreads();
    const bool isb = (cnt > 128);
    if (bx == 128) {
        if (threadIdx.x == 0) *flag = isb ? 1u : 0u;
        return;
    }
    // wpack body: blocks 129..704 -> rep = (bx-129)/72, inner block (bx-129)%72
    int rep  = (bx - 129) / 72;
    int bxin = (bx - 129) - rep * 72;
    int gid  = bxin * 256 + threadIdx.x;          // 0..18431
    int lane = gid & 63;
    int tIdx = gid >> 6;                          // 0..287
    int ct   = tIdx / 24;
    int rem  = tIdx - ct * 24;
    int c    = rem >> 1, ks = rem & 1;
    int quad = lane >> 4, l15 = lane & 15;
    const void* wsel = (ct < 4) ? Wq_ : (ct < 8 ? Wk_ : Wv_);
    int row = (ct & 3) * 16 + l15;
    int col = c * 64 + ks * 32 + quad * 8;
    uint4 w;
    if (isb) {
        w = *(const uint4*)((const unsigned short*)wsel + (size_t)row * E_ + col);
    } else {
        const float* f = (const float*)wsel + (size_t)row * E_ + col;
        float4 a = *(const float4*)f, bq = *(const float4*)(f + 4);
        w.x = f2bf(a.x)  | ((unsigned)f2bf(a.y)  << 16);
        w.y = f2bf(a.z)  | ((unsigned)f2bf(a.w)  << 16);
        w.z = f2bf(bq.x) | ((unsigned)f2bf(bq.y) << 16);
        w.w = f2bf(bq.z) | ((unsigned)f2bf(bq.w) << 16);
    }
    *(uint4*)(wp + (size_t)rep * WPSZ + (size_t)gid * 8) = w;
}

// ---------------------------------------------------------------------------
// QKV projection + RoPE, MFMA 16x16x32 bf16.
// ROUND-10 CHANGE: amortize B over 2x output rows. Cross-round model: qkv
// time ~ 70 cyc per VMEM instruction per CU (1344/CU at r8 -> ~40us loop);
// bytes are NOT the limit (2.2 B/cyc/CU vs ~10 achievable). So halve B
// instructions per output row: grid 256 (1 block/CU), each block computes
// TWO 64-row tiles; per chunk/wave: 2 A-gld_lds + 6 B-loads = 8 VMEM for
// 2x work (768/CU, -43%). launch_bounds(512,2) -> VGPR cap 256 (acc 48 +
// breg 48 + addr fits, no r7-style spill). Pipeline = r8-proven template,
// vmcnt(8) completes exactly B(c)x6 + A(c)x2, leaves 8 in flight.
// A ring [3 slots][2 tiles][8KB] = 48KB LDS.
// ---------------------------------------------------------------------------
__global__ __launch_bounds__(512, 2) void qkv_mfma_kernel(
    const void* __restrict__ x_, const unsigned short* __restrict__ wp,
    const unsigned int* __restrict__ flag,
    const float* __restrict__ cs_t, const float* __restrict__ sn_t,
    unsigned short* __restrict__ rq_p, unsigned short* __restrict__ rk_p,
    unsigned short* __restrict__ vt_p)
{
    __shared__ __align__(16) char alds[3][2][8192];   // A ring x 2 row-tiles

    const bool isb = (*flag != 0);
    const int t    = threadIdx.x;
    const int lane = t & 63;
    const int wave = t >> 6;        // 0..7
    const int quad = lane >> 4;
    const int l15  = lane & 15;
    const int row0 = blockIdx.x * 128;   // two 64-row tiles: row0, row0+64
    const int h    = wave >> 2;     // row half: mt tiles {h*2, h*2+1}
    const int cw   = wave & 3;      // col group: ct = cw*3 + nt

    // this block's wp replica (block g -> XCD g%8 -> replica g&7 XCD-local)
    const unsigned short* wpr = wp + (size_t)(blockIdx.x & (WREP - 1)) * WPSZ;

    // A stage descriptor: 1 instr/wave/chunk/tile; wave covers rows wave*8..+7.
    const unsigned aRow = (unsigned)(wave * 8 + (lane >> 3));
    const unsigned eoA  = aRow * 768u + (unsigned)(((lane & 7) ^ (lane >> 3)) * 8);

    // A fragment read byte-addrs within a slot
    unsigned aA[2][2];
    #pragma unroll
    for (int mtl = 0; mtl < 2; ++mtl) {
        unsigned rl = (unsigned)((h * 2 + mtl) * 16 + l15);
        #pragma unroll
        for (int ks = 0; ks < 2; ++ks)
            aA[mtl][ks] = rl * 128u + ((((unsigned)ks << 2) | (unsigned)quad) ^ (rl & 7u)) * 16u;
    }

    // B fragment bases (chunk stride = 1024 elems)
    const unsigned short* wbase[3][2];
    #pragma unroll
    for (int nt = 0; nt < 3; ++nt) {
        int ct = cw * 3 + nt;
        #pragma unroll
        for (int ks = 0; ks < 2; ++ks)
            wbase[nt][ks] = wpr + ((size_t)(ct * 24 + ks)) * 512 + lane * 8;
    }

    float4v acc[2][3][2];   // [tile][nt][mtl]
    #pragma unroll
    for (int t2 = 0; t2 < 2; ++t2)
        #pragma unroll
        for (int nt = 0; nt < 3; ++nt)
            #pragma unroll
            for (int mtl = 0; mtl < 2; ++mtl)
                #pragma unroll
                for (int r = 0; r < 4; ++r) acc[t2][nt][mtl][r] = 0.f;

    short8 breg[2][3][2];   // DOUBLE-buffered B frags (r5/r8-proven)

    const unsigned short* xb16a = (const unsigned short*)x_ + (size_t)row0 * E_;
    const unsigned short* xb16b = xb16a + (size_t)64 * E_;
    const float*          xb32a = (const float*)x_ + (size_t)row0 * E_;
    const float*          xb32b = xb32a + (size_t)64 * E_;

    #define LOADB(cc, sel)                                                       \
        {   int tc_ = (cc) < 11 ? (cc) : 11;                                     \
            _Pragma("unroll")                                                    \
            for (int nt_ = 0; nt_ < 3; ++nt_)                                    \
                _Pragma("unroll")                                                \
                for (int ks_ = 0; ks_ < 2; ++ks_)                                \
                    breg[sel][nt_][ks_] =                                        \
                        *(const short8*)(wbase[nt_][ks_] + tc_ * 1024);          \
        }

    // stage A for BOTH tiles of chunk cc (2 gld_lds)
    #define LOADA(cc)                                                            \
        {   int tc_ = (cc) < 11 ? (cc) : 11;                                     \
            gld_lds16(xb16a + eoA + tc_ * 64, alds[(cc) % 3][0] + wave * 1024);  \
            gld_lds16(xb16b + eoA + tc_ * 64, alds[(cc) % 3][1] + wave * 1024);  \
        }

    #define COMPUTE(cc, sel)                                                     \
        {   _Pragma("unroll")                                                    \
            for (int t2_ = 0; t2_ < 2; ++t2_) {                                  \
                const char* sb_ = alds[(cc) % 3][t2_];                           \
                _Pragma("unroll")                                                \
                for (int ks_ = 0; ks_ < 2; ++ks_) {                              \
                    short8 af0 = *(const short8*)(sb_ + aA[0][ks_]);             \
                    short8 af1 = *(const short8*)(sb_ + aA[1][ks_]);             \
                    _Pragma("unroll")                                            \
                    for (int nt_ = 0; nt_ < 3; ++nt_) {                          \
                        acc[t2_][nt_][0] = __builtin_amdgcn_mfma_f32_16x16x32_bf16( \
                            af0, breg[sel][nt_][ks_], acc[t2_][nt_][0], 0, 0, 0);   \
                        acc[t2_][nt_][1] = __builtin_amdgcn_mfma_f32_16x16x32_bf16( \
                            af1, breg[sel][nt_][ks_], acc[t2_][nt_][1], 0, 0, 0);   \
                    }                                                            \
                }                                                                \
            }                                                                    \
        }

    if (isb) {
        // prologue FIFO: [B0 x6, A0 x2, B1 x6, A1 x2] = 16 outstanding
        LOADB(0, 0);
        __builtin_amdgcn_sched_barrier(0);
        LOADA(0);
        __builtin_amdgcn_sched_barrier(0);
        LOADB(1, 1);
        __builtin_amdgcn_sched_barrier(0);
        LOADA(1);
        __builtin_amdgcn_sched_barrier(0);
        #pragma unroll
        for (int c = 0; c < 12; ++c) {
            // completes exactly B(c)x6 + A(c)x2; leaves B(c+1)x6 + A(c+1)x2
            asm volatile("s_waitcnt vmcnt(8)" ::: "memory");
            __builtin_amdgcn_s_barrier();
            LOADA(c + 2);                      // slot (c+2)%3, disjoint from c%3
            __builtin_amdgcn_sched_barrier(0);
            COMPUTE(c, c & 1);
            __builtin_amdgcn_sched_barrier(0);
            LOADB(c + 2, c & 1);               // late-issue into consumed buffer
            __builtin_amdgcn_sched_barrier(0);
        }
    } else {
        // f32 correctness path: A via reg-convert ds_write, full syncs.
        auto stageA_f = [&](int c) {
            #pragma unroll
            for (int t2 = 0; t2 < 2; ++t2) {
                const float* f = (t2 ? xb32b : xb32a) + eoA + c * 64;
                float4 a = *(const float4*)f, bq = *(const float4*)(f + 4);
                uint4 w;
                w.x = f2bf(a.x)  | ((unsigned)f2bf(a.y)  << 16);
                w.y = f2bf(a.z)  | ((unsigned)f2bf(a.w)  << 16);
                w.z = f2bf(bq.x) | ((unsigned)f2bf(bq.y) << 16);
                w.w = f2bf(bq.z) | ((unsigned)f2bf(bq.w) << 16);
                *(uint4*)(alds[c % 3][t2] + wave * 1024 + (size_t)lane * 16) = w;
            }
        };
        stageA_f(0); stageA_f(1);
        LOADB(0, 0);
        __syncthreads();
        #pragma unroll
        for (int c = 0; c < 12; ++c) {
            if (c + 2 < 12) stageA_f(c + 2);
            LOADB(c + 1, (c + 1) & 1);
            COMPUTE(c, c & 1);
            __syncthreads();
        }
    }
    #undef LOADB
    #undef LOADA
    #undef COMPUTE

    // ---- Epilogue (r3-r9 verified math), run per tile: C col=l15, row=quad*4+r.
    #pragma unroll
    for (int t2 = 0; t2 < 2; ++t2) {
        const int rt0    = row0 + t2 * 64;
        const int b      = rt0 >> 10;
        const int s_in_b = rt0 & (S_ - 1);
        #pragma unroll
        for (int nt = 0; nt < 3; ++nt) {
            int ct = cw * 3 + nt;
            int region = ct >> 2;          // 0=q, 1=k, 2=v (wave-uniform)
            int d = (ct & 3) * 16 + l15;
            if (region < 2) {
                unsigned short* dst = (region == 0) ? rq_p : rk_p;
                int ii = d >> 1;
                int ksq = d >> 5, quadq = (d >> 3) & 3, e = d & 7;
                #pragma unroll
                for (int mtl = 0; mtl < 2; ++mtl) {
                    #pragma unroll
                    for (int r = 0; r < 4; ++r) {
                        int row = rt0 + (h * 2 + mtl) * 16 + quad * 4 + r;
                        int pos = row & (S_ - 1);
                        float cs = cs_t[pos * 32 + ii];
                        float sn = sn_t[pos * 32 + ii];
                        float val = acc[t2][nt][mtl][r];
                        float partner = __shfl_xor(val, 1);   // pair col d^1 = lane^1
                        float res = (d & 1) ? fmaf(val, cs,  partner * sn)
                                            : fmaf(val, cs, -partner * sn);
                        int kt = pos >> 6, ntq = (pos >> 4) & 3, l15q = pos & 15;
                        size_t idx = ((((size_t)(b * 16 + kt) * 4 + ntq) * 2 + ksq) * 64
                                      + quadq * 16 + l15q) * 8 + e;
                        dst[idx] = f2bf(res);
                    }
                }
            } else {
                int ntv = ct & 3;          // d = ntv*16 + l15
                #pragma unroll
                for (int mtl = 0; mtl < 2; ++mtl) {
                    int sb2 = s_in_b + (h * 2 + mtl) * 16 + quad * 4;
                    int kt = sb2 >> 6, ksv = (sb2 >> 5) & 1, quadv = (sb2 >> 3) & 3, e0 = sb2 & 7;
                    ushort4 pk;
                    pk.x = f2bf(acc[t2][nt][mtl][0]);
                    pk.y = f2bf(acc[t2][nt][mtl][1]);
                    pk.z = f2bf(acc[t2][nt][mtl][2]);
                    pk.w = f2bf(acc[t2][nt][mtl][3]);
                    size_t idx = ((((size_t)(b * 16 + kt) * 4 + ntv) * 2 + ksv) * 64
                                  + quadv * 16 + l15) * 8 + e0;
                    *(ushort4*)(vt_p + idx) = pk;
                }
            }
        }
    }
}

// ---------------------------------------------------------------------------
// Flash attention — unchanged from round 9 (direct-reg K/V + causal balance
// remap: co-resident pair (g, g+256) gets complementary qt; ~16us).
// ---------------------------------------------------------------------------
__global__ __launch_bounds__(256, 2) void attn_mfma_kernel(
    const unsigned short* __restrict__ rq_p, const unsigned short* __restrict__ rk_p,
    const unsigned short* __restrict__ vt_p, const unsigned int* __restrict__ flag,
    void* __restrict__ out)
{
    __shared__ unsigned short plds[4][16][72];                 // per-wave P buffer

    const bool isb = (*flag != 0);
    const int t    = threadIdx.x;
    const int lane = t & 63;
    const int wave = t >> 6;
    const int quad = lane >> 4;
    const int l15  = lane & 15;

    // balance remap: co-resident pair (g, g+256) -> complementary qt
    const int g  = blockIdx.x;
    const int j  = g & 255;
    const int qt = (g < 256) ? (j & 15) : (15 - (j & 15));
    const int b  = (g < 256) ? (j >> 4) : (16 + (j >> 4));

    const int q0   = qt * 64 + wave * 16;
    const float scale = 0.03608439182435161f;   // 768^-0.5

    // Q A-frags from packed tile (b, kt=qt, nt=wave)
    const unsigned short* qb = rq_p + ((size_t)((b * 16 + qt) * 4 + wave) * 2) * 512;
    short8 qf0 = *(const short8*)(qb + lane * 8);
    short8 qf1 = *(const short8*)(qb + 512 + lane * 8);

    // packed tile base: tile (kt,nt,ks) at ((b*64 + kt*4 + nt)*2 + ks)*512 + lane*8
    const unsigned short* kb0 = rk_p + ((size_t)b * 128) * 512 + lane * 8;
    const unsigned short* vb0 = vt_p + ((size_t)b * 128) * 512 + lane * 8;

    float4v o[4];
    float m_[4], l_[4];
    #pragma unroll
    for (int nt = 0; nt < 4; ++nt)
        #pragma unroll
        for (int r = 0; r < 4; ++r) o[nt][r] = 0.f;
    #pragma unroll
    for (int r = 0; r < 4; ++r) { m_[r] = -1e30f; l_[r] = 0.f; }

    const int nIter = (qt + 2) >> 1;

    for (int i = 0; i < nIter; ++i) {
        const int ta = 2 * i;
        const int tb = min(ta + 1, qt);     // dup tail fully masked via logical kg
        const int ktv[2] = { ta, tb };

        // ---- K frags -> regs (coalesced 1KB/wave each) ----
        short8 kf[2][4][2];
        #pragma unroll
        for (int slot = 0; slot < 2; ++slot)
            #pragma unroll
            for (int nt = 0; nt < 4; ++nt)
                #pragma unroll
                for (int ks = 0; ks < 2; ++ks)
                    kf[slot][nt][ks] = *(const short8*)(
                        kb0 + (size_t)(ktv[slot] * 8 + nt * 2 + ks) * 512);

        // ---- S = Q K^T for both slots ----
        float sc[2][4][4];
        #pragma unroll
        for (int slot = 0; slot < 2; ++slot) {
            #pragma unroll
            for (int nt = 0; nt < 4; ++nt) {
                float4v s;
                #pragma unroll
                for (int r = 0; r < 4; ++r) s[r] = 0.f;
                s = __builtin_amdgcn_mfma_f32_16x16x32_bf16(qf0, kf[slot][nt][0], s, 0, 0, 0);
                s = __builtin_amdgcn_mfma_f32_16x16x32_bf16(qf1, kf[slot][nt][1], s, 0, 0, 0);
                #pragma unroll
                for (int r = 0; r < 4; ++r) sc[slot][nt][r] = s[r] * scale;
            }
        }

        // ---- V frags -> regs NOW (latency hides under softmax VALU) ----
        short8 vf[2][4][2];
        #pragma unroll
        for (int slot = 0; slot < 2; ++slot)
            #pragma unroll
            for (int nt = 0; nt < 4; ++nt)
                #pragma unroll
                for (int ks = 0; ks < 2; ++ks)
                    vf[slot][nt][ks] = *(const short8*)(
                        vb0 + (size_t)(ktv[slot] * 8 + nt * 2 + ks) * 512);

        // ---- causal mask (wave-uniform trigger near diagonal) ----
        if (2 * i + 1 >= qt) {
            #pragma unroll
            for (int slot = 0; slot < 2; ++slot) {
                int ktl = 2 * i + slot;     // LOGICAL tile (dup tail -> all masked)
                #pragma unroll
                for (int nt = 0; nt < 4; ++nt) {
                    int kg = ktl * 64 + nt * 16 + l15;
                    #pragma unroll
                    for (int r = 0; r < 4; ++r) {
                        int qg = q0 + quad * 4 + r;
                        if (kg > qg) sc[slot][nt][r] = -1e30f;
                    }
                }
            }
        }

        // ---- online softmax over 128 keys (16-lane reduce) ----
        float mx[4];
        #pragma unroll
        for (int r = 0; r < 4; ++r) {
            float a0 = fmaxf(fmaxf(sc[0][0][r], sc[0][1][r]), fmaxf(sc[0][2][r], sc[0][3][r]));
            float a1 = fmaxf(fmaxf(sc[1][0][r], sc[1][1][r]), fmaxf(sc[1][2][r], sc[1][3][r]));
            mx[r] = fmaxf(a0, a1);
        }
        #pragma unroll
        for (int st = 1; st < 16; st <<= 1)
            #pragma unroll
            for (int r = 0; r < 4; ++r)
                mx[r] = fmaxf(mx[r], __shfl_xor(mx[r], st));

        float al[4];
        #pragma unroll
        for (int r = 0; r < 4; ++r) {
            float mn = fmaxf(m_[r], mx[r]);
            al[r] = __expf(m_[r] - mn);
            m_[r] = mn;
        }

        float sm[4] = {0.f, 0.f, 0.f, 0.f};
        #pragma unroll
        for (int slot = 0; slot < 2; ++slot)
            #pragma unroll
            for (int nt = 0; nt < 4; ++nt)
                #pragma unroll
                for (int r = 0; r < 4; ++r) {
                    float p = __expf(sc[slot][nt][r] - m_[r]);
                    sc[slot][nt][r] = p;
                    sm[r] += p;
                }
        #pragma unroll
        for (int st = 1; st < 16; st <<= 1)
            #pragma unroll
            for (int r = 0; r < 4; ++r)
                sm[r] += __shfl_xor(sm[r], st);
        #pragma unroll
        for (int r = 0; r < 4; ++r) l_[r] = l_[r] * al[r] + sm[r];

        #pragma unroll
        for (int nt = 0; nt < 4; ++nt)
            #pragma unroll
            for (int r = 0; r < 4; ++r) o[nt][r] *= al[r];

        // ---- per slot: P -> plds (wave-local) -> A-frag; O += P V ----
        #pragma unroll
        for (int slot = 0; slot < 2; ++slot) {
            #pragma unroll
            for (int nt = 0; nt < 4; ++nt)
                #pragma unroll
                for (int r = 0; r < 4; ++r)
                    plds[wave][quad * 4 + r][nt * 16 + l15] = f2bf(sc[slot][nt][r]);
            short8 pf0 = *(const short8*)&plds[wave][l15][quad * 8];
            short8 pf1 = *(const short8*)&plds[wave][l15][32 + quad * 8];
            #pragma unroll
            for (int nt = 0; nt < 4; ++nt) {
                o[nt] = __builtin_amdgcn_mfma_f32_16x16x32_bf16(pf0, vf[slot][nt][0], o[nt], 0, 0, 0);
                o[nt] = __builtin_amdgcn_mfma_f32_16x16x32_bf16(pf1, vf[slot][nt][1], o[nt], 0, 0, 0);
            }
        }
    }

    // ---- epilogue: normalize, store per dtype ----
    float inv[4];
    #pragma unroll
    for (int r = 0; r < 4; ++r) inv[r] = 1.0f / l_[r];
    if (isb) {
        unsigned short* op = (unsigned short*)out;
        #pragma unroll
        for (int nt = 0; nt < 4; ++nt)
            #pragma unroll
            for (int r = 0; r < 4; ++r) {
                size_t row = (size_t)b * S_ + q0 + quad * 4 + r;
                op[row * HD_ + nt * 16 + l15] = f2bf(o[nt][r] * inv[r]);
            }
    } else {
        float* op = (float*)out;
        #pragma unroll
        for (int nt = 0; nt < 4; ++nt)
            #pragma unroll
            for (int r = 0; r < 4; ++r) {
                size_t row = (size_t)b * S_ + q0 + quad * 4 + r;
                op[row * HD_ + nt * 16 + l15] = o[nt][r] * inv[r];
            }
    }
}

// ---------------------------------------------------------------------------
extern "C" void kernel_launch(void* const* d_in, const int* in_sizes, int n_in,
                              void* d_out, int out_size, void* d_ws, size_t ws_size,
                              hipStream_t stream) {
    const void* x  = d_in[0];
    const void* Wq = d_in[1];
    const void* Wk = d_in[2];
    const void* Wv = d_in[3];

    // ws layout (~15 MB)
    unsigned int* flag = (unsigned int*)d_ws;
    float* cs_t = (float*)d_ws + 64;
    float* sn_t = cs_t + (size_t)S_ * 32;
    unsigned short* wp   = (unsigned short*)(sn_t + (size_t)S_ * 32);  // 8 replicas
    unsigned short* rq_p = wp + (size_t)WREP * WPSZ;
    unsigned short* rk_p = rq_p + (size_t)M_ * HD_;
    unsigned short* vt_p = rk_p + (size_t)M_ * HD_;

    hipLaunchKernelGGL(setup_kernel, dim3(129 + 72 * WREP), dim3(256), 0, stream,
                       (const unsigned int*)x, Wq, Wk, Wv, flag, cs_t, sn_t, wp);
    hipLaunchKernelGGL(qkv_mfma_kernel, dim3(M_ / 128), dim3(512), 0, stream,
                       x, wp, flag, cs_t, sn_t, rq_p, rk_p, vt_p);
    hipLaunchKernelGGL(attn_mfma_kernel, dim3(512), dim3(256), 0, stream,
                       rq_p, rk_p, vt_p, flag, d_out);
}